// Round 2
// baseline (10074.580 us; speedup 1.0000x reference)
//
#include <hip/hip_runtime.h>
#include <math.h>

// Problem constants
constexpr int NSEQ = 1280;   // B*D
constexpr int NT   = 50;     // T
constexpr int EE   = 300;    // E
constexpr int HH   = 256;    // H
constexpr int G2   = 512;    // 2H

// One block = one sequence. Thread j owns hidden unit j.
// GRU step: r,u = sigmoid([x,h] Wg + bg); c = tanh([x, r*h] Wc + bc);
// h' = u*h + (1-u)*c
__device__ __forceinline__ float gru_step(
    int j, float hj,
    const float* __restrict__ xbuf,   // LDS [E]
    const float* __restrict__ hbuf,   // LDS [H]
    float* __restrict__ rhbuf,        // LDS [H]
    const float* __restrict__ wgr,    // Wg + j        (col j, stride 512)
    const float* __restrict__ wgu,    // Wg + 256 + j
    const float* __restrict__ wcj,    // Wc + j        (col j, stride 256)
    float bgr, float bgu, float bcj)
{
    float ar = bgr, au = bgu;
    #pragma unroll 4
    for (int k = 0; k < EE; ++k) {
        float x = xbuf[k];
        ar = fmaf(x, wgr[(size_t)k * G2], ar);
        au = fmaf(x, wgu[(size_t)k * G2], au);
    }
    #pragma unroll 4
    for (int k = 0; k < HH; ++k) {
        float hh = hbuf[k];
        ar = fmaf(hh, wgr[(size_t)(EE + k) * G2], ar);
        au = fmaf(hh, wgu[(size_t)(EE + k) * G2], au);
    }
    float r = 1.0f / (1.0f + expf(-ar));
    float u = 1.0f / (1.0f + expf(-au));
    rhbuf[j] = r * hj;
    __syncthreads();   // rhbuf ready
    float ac = bcj;
    #pragma unroll 4
    for (int k = 0; k < EE; ++k)
        ac = fmaf(xbuf[k], wcj[(size_t)k * HH], ac);
    #pragma unroll 4
    for (int k = 0; k < HH; ++k)
        ac = fmaf(rhbuf[k], wcj[(size_t)(EE + k) * HH], ac);
    float c = tanhf(ac);
    return u * hj + (1.0f - u) * c;
}

__global__ __launch_bounds__(256) void han_fused(
    const int*   __restrict__ ids,   // [N, T]
    const int*   __restrict__ lens,  // [N]
    const float* __restrict__ emb,   // [VOCAB, E]
    const float* __restrict__ Wg,    // [556, 512]
    const float* __restrict__ bg,    // [512]
    const float* __restrict__ Wc,    // [556, 256]
    const float* __restrict__ bc,    // [256]
    const float* __restrict__ Wp,    // [512, 256]
    const float* __restrict__ bp,    // [256]
    const float* __restrict__ ctx,   // [256]
    float*       __restrict__ out)   // [N, 256]
{
    __shared__ float buf[NT][HH];   // fwd h outputs; overwritten by proj in bwd pass
    __shared__ float xbuf[EE];
    __shared__ float hbuf[HH];
    __shared__ float rhbuf[HH];     // r*h scratch; later reused for ctx
    __shared__ float scores[NT];

    const int n = blockIdx.x;
    const int j = threadIdx.x;
    int L = lens[n];
    if (L < 1) L = 1;
    if (L > NT) L = NT;

    const float bgr = bg[j];
    const float bgu = bg[HH + j];
    const float bcj = bc[j];
    const float bpj = bp[j];
    const float* wgr = Wg + j;
    const float* wgu = Wg + HH + j;
    const float* wcj = Wc + j;
    const float* wpj = Wp + j;

    float hj = 0.0f;
    hbuf[j] = 0.0f;

    // ---------------- forward pass ----------------
    for (int t = 0; t < L; ++t) {
        __syncthreads();                       // xbuf free to overwrite; hbuf writes visible
        int tok = ids[n * NT + t];
        for (int k = j; k < EE; k += HH) xbuf[k] = emb[(size_t)tok * EE + k];
        __syncthreads();                       // xbuf ready
        float hnew = gru_step(j, hj, xbuf, hbuf, rhbuf, wgr, wgu, wcj, bgr, bgu, bcj);
        __syncthreads();                       // all reads of hbuf/rhbuf done
        hbuf[j] = hnew;
        hj = hnew;
        buf[t][j] = hnew;
    }

    // ---------------- backward pass (+ fused projection) ----------------
    __syncthreads();
    hbuf[j] = 0.0f;
    hj = 0.0f;

    for (int s = 0; s < L; ++s) {
        int p = L - 1 - s;
        __syncthreads();
        int tok = ids[n * NT + p];
        for (int k = j; k < EE; k += HH) xbuf[k] = emb[(size_t)tok * EE + k];
        __syncthreads();
        float hnew = gru_step(j, hj, xbuf, hbuf, rhbuf, wgr, wgu, wcj, bgr, bgu, bcj);
        __syncthreads();
        hbuf[j] = hnew;     // bwd state at position p
        hj = hnew;
        __syncthreads();    // hbuf visible for projection
        // proj[p][j] = tanh([fwd[p], bwd[p]] @ Wp + bp)
        float ap = bpj;
        #pragma unroll 4
        for (int k = 0; k < HH; ++k)
            ap = fmaf(buf[p][k], wpj[(size_t)k * HH], ap);
        #pragma unroll 4
        for (int k = 0; k < HH; ++k)
            ap = fmaf(hbuf[k], wpj[(size_t)(HH + k) * HH], ap);
        float pj = tanhf(ap);
        __syncthreads();    // all reads of buf[p] done before overwrite
        buf[p][j] = pj;
    }

    // ---------------- padding rows: proj = tanh(bp) ----------------
    __syncthreads();
    float tp = tanhf(bpj);
    for (int t = L; t < NT; ++t) buf[t][j] = tp;
    rhbuf[j] = ctx[j];      // reuse rhbuf as ctx buffer
    __syncthreads();

    // ---------------- attention scores: score[t] = proj[t] . ctx ----------------
    const int w = j >> 6, l = j & 63;
    for (int t = w; t < NT; t += 4) {
        float v = 0.0f;
        #pragma unroll
        for (int m = 0; m < 4; ++m) v += buf[t][l + 64 * m] * rhbuf[l + 64 * m];
        #pragma unroll
        for (int off = 32; off > 0; off >>= 1) v += __shfl_down(v, off);
        if (l == 0) scores[t] = v;
    }
    __syncthreads();

    // ---------------- softmax over all T=50 + weighted sum ----------------
    float mx = -1e30f;
    for (int t = 0; t < NT; ++t) mx = fmaxf(mx, scores[t]);
    float sum = 0.0f, acc = 0.0f;
    for (int t = 0; t < NT; ++t) {
        float e = expf(scores[t] - mx);
        sum += e;
        acc = fmaf(e, buf[t][j], acc);
    }
    out[n * HH + j] = acc / sum;
}

extern "C" void kernel_launch(void* const* d_in, const int* in_sizes, int n_in,
                              void* d_out, int out_size, void* d_ws, size_t ws_size,
                              hipStream_t stream) {
    const int*   ids  = (const int*)  d_in[0];
    const int*   lens = (const int*)  d_in[1];
    const float* emb  = (const float*)d_in[2];
    const float* Wg   = (const float*)d_in[3];
    const float* bg   = (const float*)d_in[4];
    const float* bc_  = nullptr; (void)bc_;
    const float* Wc   = (const float*)d_in[5];
    const float* bc   = (const float*)d_in[6];
    const float* Wp   = (const float*)d_in[7];
    const float* bp   = (const float*)d_in[8];
    const float* ctx  = (const float*)d_in[9];
    float* out = (float*)d_out;

    han_fused<<<dim3(NSEQ), dim3(256), 0, stream>>>(
        ids, lens, emb, Wg, bg, Wc, bc, Wp, bp, ctx, out);
}

// Round 3
// 4910.760 us; speedup vs baseline: 2.0515x; 2.0515x over previous
//
#include <hip/hip_runtime.h>
#include <math.h>

constexpr int NSEQ = 1280;
constexpr int NT   = 50;
constexpr int EE   = 300;
constexpr int HH   = 256;
constexpr int G2   = 512;
constexpr int XH   = 556;   // E + H
constexpr int G    = 4;     // sequences per block
constexpr int NBLK = NSEQ / G;
constexpr int SORTN = 2048;
constexpr size_t FWD_ELEMS = (size_t)NSEQ * NT * HH;   // 65.536 MB of f32

union F4 { float4 v; float f[4]; };

// ---------------- length sort (descending) for balanced grouping ----------------
__global__ __launch_bounds__(1024) void sort_lens_kernel(const int* __restrict__ lens,
                                                         int* __restrict__ perm) {
    __shared__ int key[SORTN];
    const int tid = threadIdx.x;
    for (int i = tid; i < SORTN; i += 1024) {
        if (i < NSEQ) {
            int L = lens[i]; L = L < 1 ? 1 : (L > NT ? NT : L);
            key[i] = (L << 16) | i;           // unique keys -> deterministic
        } else key[i] = -1;                   // sinks to the end (descending)
    }
    __syncthreads();
    for (int k = 2; k <= SORTN; k <<= 1) {
        for (int jj = k >> 1; jj > 0; jj >>= 1) {
            for (int i = tid; i < SORTN; i += 1024) {
                int ixj = i ^ jj;
                if (ixj > i) {
                    int a = key[i], b = key[ixj];
                    bool up = ((i & k) == 0);             // descending order
                    if (up ? (a < b) : (a > b)) { key[i] = b; key[ixj] = a; }
                }
            }
            __syncthreads();
        }
    }
    for (int i = tid; i < NSEQ; i += 1024) perm[i] = key[i] & 0xFFFF;
}

// ---------------- fused HAN: 4 sequences per 256-thread block ----------------
__global__ __launch_bounds__(256) void han_main(
    const int*   __restrict__ ids,   // [N, T]
    const int*   __restrict__ lens,  // [N]
    const float* __restrict__ emb,   // [VOCAB, E]
    const float* __restrict__ Wg,    // [556, 512]
    const float* __restrict__ bg,    // [512]
    const float* __restrict__ Wc,    // [556, 256]
    const float* __restrict__ bc,    // [256]
    const float* __restrict__ Wp,    // [512, 256]
    const float* __restrict__ bp,    // [256]
    const float* __restrict__ ctx,   // [256]
    const int*   __restrict__ perm,  // [N] sorted-desc sequence ids
    float*       __restrict__ fwdws, // [N, T, H] fwd hidden states
    float*       __restrict__ out)   // [N, 256]
{
    __shared__ float xh[XH][G];      // [x(300); h(256)] per group, 16B rows
    __shared__ float red[4][G];      // per-wave score partials
    __shared__ int   shn[G], shL[G];

    const int j  = threadIdx.x;
    const int wv = j >> 6, ln = j & 63;

    if (j < G) {
        int n = perm[blockIdx.x * G + j];
        shn[j] = n;
        int L = lens[n];
        shL[j] = L < 1 ? 1 : (L > NT ? NT : L);
    }
    __syncthreads();
    int n_[G], L_[G];
    #pragma unroll
    for (int g = 0; g < G; ++g) { n_[g] = shn[g]; L_[g] = shL[g]; }
    const int Lmax = max(max(L_[0], L_[1]), max(L_[2], L_[3]));

    const float bgr = bg[j], bgu = bg[HH + j], bcj = bc[j], bpj = bp[j], ctxj = ctx[j];
    const float* __restrict__ wgr = Wg + j;
    const float* __restrict__ wgu = Wg + HH + j;
    const float* __restrict__ wcj = Wc + j;
    const float* __restrict__ wpj = Wp + j;

    float h[G] = {0.f, 0.f, 0.f, 0.f};

    // ================= forward =================
    for (int t = 0; t < Lmax; ++t) {
        __syncthreads();
        int tok[G];
        #pragma unroll
        for (int g = 0; g < G; ++g) {
            int tt = t < L_[g] ? t : L_[g] - 1;
            tok[g] = ids[n_[g] * NT + tt];
        }
        for (int k = j; k < EE; k += HH) {
            F4 xv;
            #pragma unroll
            for (int g = 0; g < G; ++g) xv.f[g] = emb[(size_t)tok[g] * EE + k];
            *(float4*)&xh[k][0] = xv.v;
        }
        *(float4*)&xh[EE + j][0] = make_float4(h[0], h[1], h[2], h[3]);
        __syncthreads();

        float ar[G], au[G];
        #pragma unroll
        for (int g = 0; g < G; ++g) { ar[g] = bgr; au[g] = bgu; }
        #pragma unroll 4
        for (int k = 0; k < XH; ++k) {
            float wr = wgr[k * G2];
            float wu = wgu[k * G2];
            F4 xv; xv.v = *(const float4*)&xh[k][0];
            #pragma unroll
            for (int g = 0; g < G; ++g) {
                ar[g] = fmaf(xv.f[g], wr, ar[g]);
                au[g] = fmaf(xv.f[g], wu, au[g]);
            }
        }
        float uu[G];
        {
            float rr[G];
            #pragma unroll
            for (int g = 0; g < G; ++g) {
                rr[g] = 1.f / (1.f + expf(-ar[g]));
                uu[g] = 1.f / (1.f + expf(-au[g]));
            }
            __syncthreads();   // gates reads of xh complete
            *(float4*)&xh[EE + j][0] =
                make_float4(rr[0]*h[0], rr[1]*h[1], rr[2]*h[2], rr[3]*h[3]);
        }
        __syncthreads();
        float ac[G] = {bcj, bcj, bcj, bcj};
        #pragma unroll 4
        for (int k = 0; k < XH; ++k) {
            float wc = wcj[k * HH];
            F4 xv; xv.v = *(const float4*)&xh[k][0];
            #pragma unroll
            for (int g = 0; g < G; ++g) ac[g] = fmaf(xv.f[g], wc, ac[g]);
        }
        #pragma unroll
        for (int g = 0; g < G; ++g) {
            if (t < L_[g]) {
                float c  = tanhf(ac[g]);
                float hn = uu[g] * h[g] + (1.f - uu[g]) * c;
                h[g] = hn;
                fwdws[((size_t)n_[g] * NT + t) * HH + j] = hn;
            }
        }
    }

    // ================= backward + fused projection + online attention =================
    float hb[G]   = {0.f, 0.f, 0.f, 0.f};
    float accO[G] = {0.f, 0.f, 0.f, 0.f};
    float mOn[G], lOn[G];
    #pragma unroll
    for (int g = 0; g < G; ++g) { mOn[g] = -3.0e38f; lOn[g] = 0.f; }

    for (int s = 0; s < Lmax; ++s) {
        int p_[G]; bool act[G];
        #pragma unroll
        for (int g = 0; g < G; ++g) { act[g] = s < L_[g]; p_[g] = act[g] ? L_[g] - 1 - s : 0; }
        __syncthreads();
        int tok[G];
        #pragma unroll
        for (int g = 0; g < G; ++g) tok[g] = ids[n_[g] * NT + p_[g]];
        for (int k = j; k < EE; k += HH) {
            F4 xv;
            #pragma unroll
            for (int g = 0; g < G; ++g) xv.f[g] = emb[(size_t)tok[g] * EE + k];
            *(float4*)&xh[k][0] = xv.v;
        }
        *(float4*)&xh[EE + j][0] = make_float4(hb[0], hb[1], hb[2], hb[3]);
        __syncthreads();

        float ar[G], au[G];
        #pragma unroll
        for (int g = 0; g < G; ++g) { ar[g] = bgr; au[g] = bgu; }
        #pragma unroll 4
        for (int k = 0; k < XH; ++k) {
            float wr = wgr[k * G2];
            float wu = wgu[k * G2];
            F4 xv; xv.v = *(const float4*)&xh[k][0];
            #pragma unroll
            for (int g = 0; g < G; ++g) {
                ar[g] = fmaf(xv.f[g], wr, ar[g]);
                au[g] = fmaf(xv.f[g], wu, au[g]);
            }
        }
        float uu[G];
        {
            float rr[G];
            #pragma unroll
            for (int g = 0; g < G; ++g) {
                rr[g] = 1.f / (1.f + expf(-ar[g]));
                uu[g] = 1.f / (1.f + expf(-au[g]));
            }
            __syncthreads();
            *(float4*)&xh[EE + j][0] =
                make_float4(rr[0]*hb[0], rr[1]*hb[1], rr[2]*hb[2], rr[3]*hb[3]);
        }
        __syncthreads();
        float ac[G] = {bcj, bcj, bcj, bcj};
        #pragma unroll 4
        for (int k = 0; k < XH; ++k) {
            float wc = wcj[k * HH];
            F4 xv; xv.v = *(const float4*)&xh[k][0];
            #pragma unroll
            for (int g = 0; g < G; ++g) ac[g] = fmaf(xv.f[g], wc, ac[g]);
        }
        #pragma unroll
        for (int g = 0; g < G; ++g) {
            if (act[g]) {
                float c = tanhf(ac[g]);
                hb[g] = uu[g] * hb[g] + (1.f - uu[g]) * c;
            }
        }

        // ---- projection: proj = tanh([fwd(p), hb] @ Wp + bp), rows 0..511 of xh ----
        __syncthreads();   // cand reads done; safe to overwrite xh
        {
            F4 fv;
            #pragma unroll
            for (int g = 0; g < G; ++g)
                fv.f[g] = fwdws[((size_t)n_[g] * NT + p_[g]) * HH + j];
            *(float4*)&xh[j][0]      = fv.v;
            *(float4*)&xh[HH + j][0] = make_float4(hb[0], hb[1], hb[2], hb[3]);
        }
        __syncthreads();
        float ap[G] = {bpj, bpj, bpj, bpj};
        #pragma unroll 4
        for (int k = 0; k < G2; ++k) {
            float wp = wpj[k * HH];
            F4 xv; xv.v = *(const float4*)&xh[k][0];
            #pragma unroll
            for (int g = 0; g < G; ++g) ap[g] = fmaf(xv.f[g], wp, ap[g]);
        }
        float pj[G], sv[G];
        #pragma unroll
        for (int g = 0; g < G; ++g) { pj[g] = tanhf(ap[g]); sv[g] = pj[g] * ctxj; }
        #pragma unroll
        for (int off = 32; off; off >>= 1) {
            #pragma unroll
            for (int g = 0; g < G; ++g) sv[g] += __shfl_down(sv[g], off);
        }
        if (ln == 0) {
            #pragma unroll
            for (int g = 0; g < G; ++g) red[wv][g] = sv[g];
        }
        __syncthreads();
        #pragma unroll
        for (int g = 0; g < G; ++g) {
            if (act[g]) {
                float sg = red[0][g] + red[1][g] + red[2][g] + red[3][g];
                float mn  = fmaxf(mOn[g], sg);
                float scl = expf(mOn[g] - mn);
                float w   = expf(sg - mn);
                accO[g] = accO[g] * scl + w * pj[g];
                lOn[g]  = lOn[g]  * scl + w;
                mOn[g]  = mn;
            }
        }
    }

    // ---- padding rows: proj = tanh(bp), count = NT - L ----
    const float tp = tanhf(bpj);
    __syncthreads();           // done with red from the loop
    float svp = tp * ctxj;
    #pragma unroll
    for (int off = 32; off; off >>= 1) svp += __shfl_down(svp, off);
    if (ln == 0) red[wv][0] = svp;
    __syncthreads();
    const float spad = red[0][0] + red[1][0] + red[2][0] + red[3][0];
    #pragma unroll
    for (int g = 0; g < G; ++g) {
        float a = accO[g], l = lOn[g], m = mOn[g];
        int npad = NT - L_[g];
        if (npad > 0) {
            float mn  = fmaxf(m, spad);
            float scl = expf(m - mn);
            float w   = expf(spad - mn) * (float)npad;
            a = a * scl + w * tp;
            l = l * scl + w;
        }
        out[(size_t)n_[g] * HH + j] = a / l;
    }
}

extern "C" void kernel_launch(void* const* d_in, const int* in_sizes, int n_in,
                              void* d_out, int out_size, void* d_ws, size_t ws_size,
                              hipStream_t stream) {
    const int*   ids  = (const int*)  d_in[0];
    const int*   lens = (const int*)  d_in[1];
    const float* emb  = (const float*)d_in[2];
    const float* Wg   = (const float*)d_in[3];
    const float* bg   = (const float*)d_in[4];
    const float* Wc   = (const float*)d_in[5];
    const float* bc   = (const float*)d_in[6];
    const float* Wp   = (const float*)d_in[7];
    const float* bp   = (const float*)d_in[8];
    const float* ctx  = (const float*)d_in[9];
    float* out = (float*)d_out;

    float* fwdws = (float*)d_ws;
    int*   perm  = (int*)((char*)d_ws + FWD_ELEMS * sizeof(float));

    sort_lens_kernel<<<dim3(1), dim3(1024), 0, stream>>>(lens, perm);
    han_main<<<dim3(NBLK), dim3(256), 0, stream>>>(
        ids, lens, emb, Wg, bg, Wc, bc, Wp, bp, ctx, perm, fwdws, out);
}

// Round 4
// 2549.894 us; speedup vs baseline: 3.9510x; 1.9259x over previous
//
#include <hip/hip_runtime.h>
#include <hip/hip_bf16.h>
#include <math.h>

constexpr int NSEQ = 1280;
constexpr int NT   = 50;
constexpr int EE   = 300;
constexpr int HH   = 256;
constexpr int G2   = 512;
constexpr int XH   = 556;   // E + H
constexpr int G    = 4;     // sequences per block (GRU kernel)
constexpr int NBLK = NSEQ / G;   // 320 groups
constexpr int SORTN = 2048;
constexpr size_t HWS_ELEMS = (size_t)2 * NSEQ * NT * HH;   // fwd+bwd bf16 states

union F4 { float4 v; float f[4]; };

// ---------------- length sort (descending) for balanced grouping ----------------
__global__ __launch_bounds__(1024) void sort_lens_kernel(const int* __restrict__ lens,
                                                         int* __restrict__ perm) {
    __shared__ int key[SORTN];
    const int tid = threadIdx.x;
    for (int i = tid; i < SORTN; i += 1024) {
        if (i < NSEQ) {
            int L = lens[i]; L = L < 1 ? 1 : (L > NT ? NT : L);
            key[i] = (L << 16) | i;
        } else key[i] = -1;
    }
    __syncthreads();
    for (int k = 2; k <= SORTN; k <<= 1) {
        for (int jj = k >> 1; jj > 0; jj >>= 1) {
            for (int i = tid; i < SORTN; i += 1024) {
                int ixj = i ^ jj;
                if (ixj > i) {
                    int a = key[i], b = key[ixj];
                    bool up = ((i & k) == 0);
                    if (up ? (a < b) : (a > b)) { key[i] = b; key[ixj] = a; }
                }
            }
            __syncthreads();
        }
    }
    for (int i = tid; i < NSEQ; i += 1024) perm[i] = key[i] & 0xFFFF;
}

// ---------------- GRU, one direction per block ----------------
// blocks [0, NBLK): forward chains;  [NBLK, 2*NBLK): backward chains.
// Writes h states (bf16) to hws: fwd at [n][t][j], bwd at [NSEQ + n][t][j].
__global__ __launch_bounds__(256) void gru_dir(
    const int*   __restrict__ ids,   // [N, T]
    const int*   __restrict__ lens,  // [N]
    const float* __restrict__ emb,   // [VOCAB, E]
    const float* __restrict__ Wg,    // [556, 512]
    const float* __restrict__ bg,    // [512]
    const float* __restrict__ Wc,    // [556, 256]
    const float* __restrict__ bc,    // [256]
    const int*   __restrict__ perm,  // [N] sorted-desc sequence ids
    __hip_bfloat16* __restrict__ hws)
{
    __shared__ float xh[XH][G];      // [x(300); h(256)] per group
    __shared__ int   shn[G], shL[G];

    const int j = threadIdx.x;
    const bool isf = (blockIdx.x < NBLK);
    const int gid = isf ? blockIdx.x : blockIdx.x - NBLK;

    if (j < G) {
        int n = perm[gid * G + j];
        shn[j] = n;
        int L = lens[n];
        shL[j] = L < 1 ? 1 : (L > NT ? NT : L);
    }
    __syncthreads();
    int n_[G], L_[G];
    #pragma unroll
    for (int g = 0; g < G; ++g) { n_[g] = shn[g]; L_[g] = shL[g]; }
    const int Lmax = max(max(L_[0], L_[1]), max(L_[2], L_[3]));

    const float bgr = bg[j], bgu = bg[HH + j], bcj = bc[j];
    const float* __restrict__ wgr = Wg + j;
    const float* __restrict__ wgu = Wg + HH + j;
    const float* __restrict__ wcj = Wc + j;

    __hip_bfloat16* __restrict__ hw = hws + (isf ? (size_t)0 : (size_t)NSEQ * NT * HH);

    float h[G] = {0.f, 0.f, 0.f, 0.f};

    for (int s = 0; s < Lmax; ++s) {
        int t_[G]; bool act[G];
        #pragma unroll
        for (int g = 0; g < G; ++g) {
            act[g] = s < L_[g];
            t_[g] = isf ? (act[g] ? s : L_[g] - 1)
                        : (act[g] ? L_[g] - 1 - s : 0);
        }
        __syncthreads();                 // previous-step reads of xh complete
        int tok[G];
        #pragma unroll
        for (int g = 0; g < G; ++g) tok[g] = ids[n_[g] * NT + t_[g]];
        for (int k = j; k < EE; k += HH) {
            F4 xv;
            #pragma unroll
            for (int g = 0; g < G; ++g) xv.f[g] = emb[(size_t)tok[g] * EE + k];
            *(float4*)&xh[k][0] = xv.v;
        }
        *(float4*)&xh[EE + j][0] = make_float4(h[0], h[1], h[2], h[3]);
        __syncthreads();

        float ar[G], au[G];
        #pragma unroll
        for (int g = 0; g < G; ++g) { ar[g] = bgr; au[g] = bgu; }
        #pragma unroll 4
        for (int k = 0; k < XH; ++k) {
            float wr = wgr[k * G2];
            float wu = wgu[k * G2];
            F4 xv; xv.v = *(const float4*)&xh[k][0];
            #pragma unroll
            for (int g = 0; g < G; ++g) {
                ar[g] = fmaf(xv.f[g], wr, ar[g]);
                au[g] = fmaf(xv.f[g], wu, au[g]);
            }
        }
        float uu[G];
        {
            float rr[G];
            #pragma unroll
            for (int g = 0; g < G; ++g) {
                rr[g] = 1.f / (1.f + expf(-ar[g]));
                uu[g] = 1.f / (1.f + expf(-au[g]));
            }
            __syncthreads();             // gates reads of xh complete
            *(float4*)&xh[EE + j][0] =
                make_float4(rr[0]*h[0], rr[1]*h[1], rr[2]*h[2], rr[3]*h[3]);
        }
        __syncthreads();
        float ac[G] = {bcj, bcj, bcj, bcj};
        #pragma unroll 4
        for (int k = 0; k < XH; ++k) {
            float wc = wcj[k * HH];
            F4 xv; xv.v = *(const float4*)&xh[k][0];
            #pragma unroll
            for (int g = 0; g < G; ++g) ac[g] = fmaf(xv.f[g], wc, ac[g]);
        }
        #pragma unroll
        for (int g = 0; g < G; ++g) {
            if (act[g]) {
                float c  = tanhf(ac[g]);
                float hn = uu[g] * h[g] + (1.f - uu[g]) * c;
                h[g] = hn;
                hw[((size_t)n_[g] * NT + t_[g]) * HH + j] = __float2bfloat16(hn);
            }
        }
    }
}

// ---------------- projection + attention, one block per sequence ----------------
__global__ __launch_bounds__(256) void proj_attn(
    const int*   __restrict__ lens,
    const float* __restrict__ Wp,    // [512, 256]
    const float* __restrict__ bp,    // [256]
    const float* __restrict__ ctx,   // [256]
    const __hip_bfloat16* __restrict__ hws,
    float*       __restrict__ out)   // [N, 256]
{
    __shared__ float encs[G2][4];    // 4 rows of enc, interleaved for float4 reads
    __shared__ float red[4][4];      // [wave][r]

    const int n = blockIdx.x, j = threadIdx.x;
    const int wv = j >> 6, ln = j & 63;
    int L = lens[n]; L = L < 1 ? 1 : (L > NT ? NT : L);

    const float bpj = bp[j], ctxj = ctx[j];
    const float* __restrict__ wpj = Wp + j;
    const __hip_bfloat16* __restrict__ fw = hws + (size_t)n * NT * HH;
    const __hip_bfloat16* __restrict__ bw = hws + (size_t)(NSEQ + n) * NT * HH;

    float accO = 0.f, mOn = -3.0e38f, lOn = 0.f;

    for (int t0 = 0; t0 < L; t0 += 4) {
        __syncthreads();                       // prior reads of encs/red complete
        #pragma unroll
        for (int r = 0; r < 4; ++r) {
            int t = t0 + r; if (t > L - 1) t = L - 1;
            encs[j][r]      = __bfloat162float(fw[(size_t)t * HH + j]);
            encs[HH + j][r] = __bfloat162float(bw[(size_t)t * HH + j]);
        }
        __syncthreads();

        float ap[4] = {bpj, bpj, bpj, bpj};
        #pragma unroll 4
        for (int k = 0; k < G2; ++k) {
            float w = wpj[k * HH];
            F4 ev; ev.v = *(const float4*)&encs[k][0];
            #pragma unroll
            for (int r = 0; r < 4; ++r) ap[r] = fmaf(ev.f[r], w, ap[r]);
        }
        const int R = (L - t0) < 4 ? (L - t0) : 4;
        float pjv[4];
        #pragma unroll
        for (int r = 0; r < 4; ++r) {
            pjv[r] = tanhf(ap[r]);
            float sv = pjv[r] * ctxj;
            #pragma unroll
            for (int off = 32; off; off >>= 1) sv += __shfl_down(sv, off);
            if (ln == 0) red[wv][r] = sv;
        }
        __syncthreads();
        #pragma unroll
        for (int r = 0; r < 4; ++r) {
            if (r < R) {
                float sg = red[0][r] + red[1][r] + red[2][r] + red[3][r];
                float mn  = fmaxf(mOn, sg);
                float scl = expf(mOn - mn);
                float w   = expf(sg - mn);
                accO = accO * scl + w * pjv[r];
                lOn  = lOn  * scl + w;
                mOn  = mn;
            }
        }
    }

    // padding rows: proj = tanh(bp), count NT - L
    const float tp = tanhf(bpj);
    __syncthreads();
    float svp = tp * ctxj;
    #pragma unroll
    for (int off = 32; off; off >>= 1) svp += __shfl_down(svp, off);
    if (ln == 0) red[wv][0] = svp;
    __syncthreads();
    const float spad = red[0][0] + red[1][0] + red[2][0] + red[3][0];

    float a = accO, l = lOn, m = mOn;
    int npad = NT - L;
    if (npad > 0) {
        float mn  = fmaxf(m, spad);
        float scl = expf(m - mn);
        float w   = expf(spad - mn) * (float)npad;
        a = a * scl + w * tp;
        l = l * scl + w;
    }
    out[(size_t)n * HH + j] = a / l;
}

extern "C" void kernel_launch(void* const* d_in, const int* in_sizes, int n_in,
                              void* d_out, int out_size, void* d_ws, size_t ws_size,
                              hipStream_t stream) {
    const int*   ids  = (const int*)  d_in[0];
    const int*   lens = (const int*)  d_in[1];
    const float* emb  = (const float*)d_in[2];
    const float* Wg   = (const float*)d_in[3];
    const float* bg   = (const float*)d_in[4];
    const float* Wc   = (const float*)d_in[5];
    const float* bc   = (const float*)d_in[6];
    const float* Wp   = (const float*)d_in[7];
    const float* bp   = (const float*)d_in[8];
    const float* ctx  = (const float*)d_in[9];
    float* out = (float*)d_out;

    __hip_bfloat16* hws = (__hip_bfloat16*)d_ws;
    int* perm = (int*)((char*)d_ws + HWS_ELEMS * sizeof(__hip_bfloat16));

    sort_lens_kernel<<<dim3(1), dim3(1024), 0, stream>>>(lens, perm);
    gru_dir<<<dim3(2 * NBLK), dim3(256), 0, stream>>>(
        ids, lens, emb, Wg, bg, Wc, bc, perm, hws);
    proj_attn<<<dim3(NSEQ), dim3(256), 0, stream>>>(
        lens, Wp, bp, ctx, hws, out);
}